// Round 8
// baseline (124.123 us; speedup 1.0000x reference)
//
#include <hip/hip_runtime.h>
#include <hip/hip_bf16.h>

// Problem constants
#define BB    16
#define CREF  256
#define CINC  256
#define COUTC 256
#define KKN   4
#define HH    56
#define WWW   56
#define HIDDEN 65
#define NPIX  3136          // 56*56
#define PPIX  3364          // 58*58 padded
#define TEMP  34.0f

typedef __bf16 bf16x8 __attribute__((ext_vector_type(8)));
typedef float  f32x4  __attribute__((ext_vector_type(4)));

// ---------------- ws layout (bytes) ----------------
#define WS_ATTN   0
#define WS_AGGB   4096
#define WS_POOL   24576
#define WS_AGGW   65536      // 16*2*8*36864 elems bf16 = 18,874,368 B  [b][ch][cb8][tap][cing][cout128][cin8]
#define WS_XPAD   19005440   // 16*3364*256*2 = 27,557,888 (+slack for staging overread)

// conv LDS sizing
#define XBUF  40960          // [cg4][row10][col64][16B]
#define ABUF  73728          // [tap9][cing4][cout128][16B]
#define LDS_TOT (2*XBUF + ABUF)   // 155,648 B

// ---------- 1. adaptive avg pool (one wave per (b,c)) + xpad border zeroing ----------
__global__ void pool_k(const float* __restrict__ ref, float* __restrict__ pooled,
                       __bf16* __restrict__ xpad) {
    int wid = threadIdx.x >> 6, lane = threadIdx.x & 63;
    int gw = blockIdx.x * 4 + wid;            // 0..4095 = b*256+c
    const float4* r4 = reinterpret_cast<const float4*>(ref) + (size_t)gw * 784;
    float s = 0.f;
    for (int i = lane; i < 784; i += 64) {
        float4 v = r4[i];
        s += v.x + v.y + v.z + v.w;
    }
    for (int o = 32; o; o >>= 1) s += __shfl_xor(s, o);
    if (lane == 0) pooled[gw] = s * (1.0f / (float)NPIX);

    // border zeroing: 16 b * 228 border positions, 512B rows
    if (gw < 3648) {
        int b = gw / 228, i = gw % 228;
        int ph, pw;
        if (i < 58)       { ph = 0;        pw = i; }
        else if (i < 116) { ph = 57;       pw = i - 58; }
        else if (i < 172) { ph = i - 115;  pw = 0; }
        else              { ph = i - 171;  pw = 57; }
        uint2* dst = (uint2*)(xpad + ((size_t)b * PPIX + ph * 58 + pw) * 256);
        dst[lane] = (uint2){0u, 0u};
    }
}

// ---------- 2. attention + agg bias: one block per batch sample ----------
__global__ void attn_k(const float* __restrict__ pooled, const float* __restrict__ fc1w,
                       const float* __restrict__ fc2w, const float* __restrict__ fc2b,
                       const float* __restrict__ bias,
                       float* __restrict__ attn, float* __restrict__ aggb) {
    int b = blockIdx.x;
    int t = threadIdx.x;
    __shared__ float sh[HIDDEN + 7];
    __shared__ float sl[KKN];
    __shared__ float sa[KKN];
    const float* prow = pooled + b * CREF;
    {
        int j = t >> 2, sub = t & 3;
        const float4* w4 = (const float4*)(fc1w + j * CREF + sub * 64);
        const float4* p4 = (const float4*)(prow + sub * 64);
        float s = 0.f;
#pragma unroll
        for (int k = 0; k < 16; ++k) {
            float4 w = w4[k], p = p4[k];
            s += w.x * p.x + w.y * p.y + w.z * p.z + w.w * p.w;
        }
        s += __shfl_xor(s, 1); s += __shfl_xor(s, 2);
        if (sub == 0) sh[j] = fmaxf(s, 0.f);
    }
    if (t < 4) {   // j = 64
        const float4* w4 = (const float4*)(fc1w + 64 * CREF + t * 64);
        const float4* p4 = (const float4*)(prow + t * 64);
        float s = 0.f;
#pragma unroll
        for (int k = 0; k < 16; ++k) {
            float4 w = w4[k], p = p4[k];
            s += w.x * p.x + w.y * p.y + w.z * p.z + w.w * p.w;
        }
        s += __shfl_xor(s, 1); s += __shfl_xor(s, 2);
        if (t == 0) sh[64] = fmaxf(s, 0.f);
    }
    __syncthreads();
    if (t < KKN) {
        float s = fc2b[t];
        for (int j = 0; j < HIDDEN; ++j) s += sh[j] * fc2w[t * HIDDEN + j];
        sl[t] = s * (1.0f / TEMP);
    }
    __syncthreads();
    if (t == 0) {
        float m = fmaxf(fmaxf(sl[0], sl[1]), fmaxf(sl[2], sl[3]));
        float e0 = expf(sl[0] - m), e1 = expf(sl[1] - m);
        float e2 = expf(sl[2] - m), e3 = expf(sl[3] - m);
        float inv = 1.f / (e0 + e1 + e2 + e3);
        sa[0] = e0 * inv; sa[1] = e1 * inv; sa[2] = e2 * inv; sa[3] = e3 * inv;
        attn[b * 4 + 0] = sa[0]; attn[b * 4 + 1] = sa[1];
        attn[b * 4 + 2] = sa[2]; attn[b * 4 + 3] = sa[3];
    }
    __syncthreads();
    {
        float s = 0.f;
#pragma unroll
        for (int k = 0; k < KKN; ++k) s += sa[k] * bias[k * COUTC + t];
        aggb[b * COUTC + t] = s;
    }
}

// ---------- 3. blend weights -> bf16 [b][ch][cb8][tap][cing][cout128][cin8] ----------
// grid (32 cout-blocks, 8 cb8), block 256 = (cout 8) x (cr 32)
__global__ void aggw_k(const float* __restrict__ attn, const float* __restrict__ weight,
                       __bf16* __restrict__ aggw) {
    __shared__ float s_attn[64];
    int t = threadIdx.x;
    int co = t >> 5, cr = t & 31;
    int cout = blockIdx.x * 8 + co;       // 0..255
    int cb8 = blockIdx.y;                 // 0..7
    int cin = cb8 * 32 + cr;
    if (t < 64) s_attn[t] = attn[t];
    __syncthreads();
    float w[4][9];
#pragma unroll
    for (int k = 0; k < 4; ++k) {
        const float* wp = weight + ((size_t)(k * 256 + cout) * 256 + cin) * 9;
#pragma unroll
        for (int tp = 0; tp < 9; ++tp) w[k][tp] = wp[tp];
    }
    int ch = cout >> 7, coutl = cout & 127;
    int cing = cr >> 3, cinr = cr & 7;
    for (int b = 0; b < BB; ++b) {
        float a0 = s_attn[b * 4 + 0], a1 = s_attn[b * 4 + 1];
        float a2 = s_attn[b * 4 + 2], a3 = s_attn[b * 4 + 3];
#pragma unroll
        for (int tap = 0; tap < 9; ++tap) {
            float v = a0 * w[0][tap] + a1 * w[1][tap] + a2 * w[2][tap] + a3 * w[3][tap];
            size_t e = (size_t)((b * 2 + ch) * 8 + cb8) * 36864 +
                       (tap * 4 + cing) * 1024 + coutl * 8 + cinr;
            aggw[e] = (__bf16)v;
        }
    }
}

// ---------- 4. x -> padded NHWC bf16 (interior, tiled transpose) ----------
__global__ void xpad_int_k(const float* __restrict__ x, __bf16* __restrict__ xpad) {
    __shared__ float tile[64][65];
    int pt = blockIdx.x;      // 0..48 pixel tile (64 px)
    int cg = blockIdx.y;      // 0..3 cin group (64 cins)
    int b  = blockIdx.z;
    int q = threadIdx.x >> 6, l = threadIdx.x & 63;
    for (int k = 0; k < 16; ++k) {
        int cl = q * 16 + k;
        tile[cl][l] = x[((size_t)(b * 256 + cg * 64 + cl)) * NPIX + pt * 64 + l];
    }
    __syncthreads();
    for (int k = 0; k < 16; ++k) {
        int pl = q * 16 + k;
        int pixel = pt * 64 + pl;
        int h = pixel / 56, w = pixel - h * 56;
        xpad[(((size_t)b * PPIX + (h + 1) * 58 + (w + 1)) * 256) + cg * 64 + l] =
            (__bf16)tile[l][pl];
    }
}

// ---------- 5. conv: implicit GEMM, tap-level software-pipelined fragment reads ----------
// block: 128 couts x 8 output rows; 8 waves, wave = 128 couts x 1 row (Mr=8, Nr=4).
// LDS: X dbuf 2x40KB ([cg4][row10][col64][16B]) + A 73.7KB in 3 thirds of 3 taps.
// Per cb8: 3 sub-steps of 3 taps. WITHIN a sub-step, frag reads for tap t+1 are
// issued (into the alternate register set) BEFORE tap t's MFMA cluster, pinned by
// sched_barrier(0), so the LDS pipe runs under the matrix pipe. Staging ledger
// and counted-vmcnt barriers identical to round 7 (verified).
__global__ __launch_bounds__(512, 2) void conv_k(const __bf16* __restrict__ xpad,
                                                 const __bf16* __restrict__ aggw,
                                                 const float* __restrict__ aggb,
                                                 float* __restrict__ out) {
    extern __shared__ __attribute__((aligned(16))) char smem[];
    char* xs = smem;                 // 2 X buffers
    char* as = smem + 2 * XBUF;      // A buffer (3 thirds of 24KB)

    const int orig = blockIdx.x;
    const int logical = (orig & 7) * 28 + (orig >> 3);   // bijective, 224 = 8*28
    const int b  = logical / 14;
    const int r  = logical - b * 14;
    const int rp = r >> 1;            // 0..6 row-octet
    const int ch = r & 1;             // cout half
    const int tid = threadIdx.x;
    const int wid = tid >> 6, lane = tid & 63;
    const int l15 = lane & 15, l4 = lane >> 4;
    const int h0 = rp * 8;            // top padded row staged (rows h0..h0+9)

    const char* xb  = (const char*)xpad + (size_t)b * PPIX * 512;
    const char* awb = (const char*)aggw + (size_t)((b * 2 + ch) * 8) * ABUF;

    f32x4 acc[8][4];
#pragma unroll
    for (int m = 0; m < 8; ++m)
#pragma unroll
        for (int n = 0; n < 4; ++n) acc[m][n] = (f32x4){0.f, 0.f, 0.f, 0.f};

    bf16x8 af[2][8];    // double-buffered A fragments (static indices only)
    bf16x8 bf[2][4];    // double-buffered B fragments

    // stage X K-block c into buffer buf: 40 x 1KB, 5 per wave
    auto XSTAGE = [&](int buf, int c) {
#pragma unroll
        for (int j = 0; j < 5; ++j) {
            int k = wid * 5 + j;             // 0..39
            int cg = k / 10, row = k - cg * 10;
            const char* src = xb + (size_t)((h0 + row) * 58 + lane) * 512 + c * 64 + cg * 16;
            __builtin_amdgcn_global_load_lds(
                (const __attribute__((address_space(1))) void*)src,
                (__attribute__((address_space(3))) void*)(xs + buf * XBUF + k * 1024),
                16, 0, 0);
        }
    };
    // stage A third (taps 3*third..3*third+2) of K-block c: 24 x 1KB, 3 per wave
    auto ASTAGE3 = [&](int third, int c) {
#pragma unroll
        for (int j = 0; j < 3; ++j) {
            int k = third * 24 + wid * 3 + j;
            const char* src = awb + (size_t)c * ABUF + k * 1024 + lane * 16;
            __builtin_amdgcn_global_load_lds(
                (const __attribute__((address_space(1))) void*)src,
                (__attribute__((address_space(3))) void*)(as + k * 1024),
                16, 0, 0);
        }
    };

#define LOADF(S, T, LB) do { \
    _Pragma("unroll") \
    for (int m_ = 0; m_ < 8; ++m_) \
        af[S][m_] = *(const bf16x8*)(as + ((T) * 4 + l4) * 2048 + (m_ * 16 + l15) * 16); \
    { const int kh_ = (T) / 3, kw_ = (T) - kh_ * 3; \
      _Pragma("unroll") \
      for (int nf_ = 0; nf_ < 4; ++nf_) \
          bf[S][nf_] = *(const bf16x8*)((LB) + \
              (((l4 * 10 + wid + kh_) * 64) + nf_ * 16 + l15 + kw_) * 16); } \
} while (0)

#define FMAS(S) do { \
    __builtin_amdgcn_s_setprio(1); \
    _Pragma("unroll") \
    for (int nf_ = 0; nf_ < 4; ++nf_) \
        _Pragma("unroll") \
        for (int m_ = 0; m_ < 8; ++m_) \
            acc[m_][nf_] = __builtin_amdgcn_mfma_f32_16x16x32_bf16( \
                af[S][m_], bf[S][nf_], acc[m_][nf_], 0, 0, 0); \
    __builtin_amdgcn_s_setprio(0); \
} while (0)

#define SB __builtin_amdgcn_sched_barrier(0)

#define SUBBAR(N) do { \
        asm volatile("s_waitcnt vmcnt(" #N ")" ::: "memory"); \
        __builtin_amdgcn_s_barrier(); \
        __builtin_amdgcn_sched_barrier(0); } while (0)

// one sub-step: taps T0,T0+1,T0+2 with frag-read pipelining; STAGES = staging issues
#define SUBSTEP(T0, LB, STAGES) do { \
    LOADF(0, T0, LB); \
    STAGES; \
    SB; \
    LOADF(1, (T0) + 1, LB); \
    SB; \
    FMAS(0); \
    SB; \
    LOADF(0, (T0) + 2, LB); \
    SB; \
    FMAS(1); \
    SB; \
    FMAS(0); \
} while (0)

    // prologue: X(0), A-thirds 0,1 of step 0; A1(0) stays in flight
    XSTAGE(0, 0);
    ASTAGE3(0, 0);
    ASTAGE3(1, 0);
    SUBBAR(3);

    int cur = 0;
    for (int c = 0; c < 7; ++c) {
        const char* lb = xs + cur * XBUF;
        // sub0: taps 0-2 (A0(c)); issue A2(c) + X(c+1)
        SUBSTEP(0, lb, { ASTAGE3(2, c); XSTAGE(cur ^ 1, c + 1); });
        SUBBAR(8);                        // A1(c) landed; A2+X in flight
        // sub1: taps 3-5 (A1(c)); issue A0(c+1)
        SUBSTEP(3, lb, { ASTAGE3(0, c + 1); });
        SUBBAR(8);                        // A2(c) landed; X+A0 in flight
        // sub2: taps 6-8 (A2(c)); issue A1(c+1)
        SUBSTEP(6, lb, { ASTAGE3(1, c + 1); });
        SUBBAR(3);                        // X(c+1)+A0(c+1) landed; A1(c+1) in flight
        cur ^= 1;
    }
    {   // step 7 (peeled, no next-step staging)
        const char* lb = xs + cur * XBUF;
        SUBSTEP(0, lb, { ASTAGE3(2, 7); });
        SUBBAR(3);                        // A1(7) landed
        SUBSTEP(3, lb, { });
        SUBBAR(0);                        // A2(7) landed
        SUBSTEP(6, lb, { });
    }
#undef SUBSTEP
#undef SUBBAR
#undef SB
#undef FMAS
#undef LOADF

    const int row = rp * 8 + wid;             // output row
#pragma unroll
    for (int m = 0; m < 8; ++m) {
#pragma unroll
        for (int i = 0; i < 4; ++i) {
            int cout = ch * 128 + m * 16 + l4 * 4 + i;
            float bv = aggb[b * COUTC + cout];
            float* op = out + ((size_t)(b * COUTC + cout) * NPIX + row * 56);
#pragma unroll
            for (int nf = 0; nf < 3; ++nf)
                __builtin_nontemporal_store(acc[m][nf][i] + bv, op + nf * 16 + l15);
            if (l15 < 8)
                __builtin_nontemporal_store(acc[m][3][i] + bv, op + 48 + l15);
        }
    }
}

extern "C" void kernel_launch(void* const* d_in, const int* in_sizes, int n_in,
                              void* d_out, int out_size, void* d_ws, size_t ws_size,
                              hipStream_t stream) {
    (void)in_sizes; (void)n_in; (void)out_size; (void)ws_size;
    const float* ref    = (const float*)d_in[0];
    const float* x      = (const float*)d_in[1];
    const float* fc1w   = (const float*)d_in[2];
    const float* fc2w   = (const float*)d_in[3];
    const float* fc2b   = (const float*)d_in[4];
    const float* weight = (const float*)d_in[5];
    const float* bias   = (const float*)d_in[6];
    float* out = (float*)d_out;
    char* ws = (char*)d_ws;

    float*  attn   = (float*)(ws + WS_ATTN);
    float*  aggb   = (float*)(ws + WS_AGGB);
    float*  pooled = (float*)(ws + WS_POOL);
    __bf16* aggw   = (__bf16*)(ws + WS_AGGW);
    __bf16* xpad   = (__bf16*)(ws + WS_XPAD);

    // allow >64KB dynamic LDS for conv_k (deterministic, capture-safe host call)
    hipFuncSetAttribute((const void*)conv_k,
                        hipFuncAttributeMaxDynamicSharedMemorySize, LDS_TOT);

    pool_k<<<1024, 256, 0, stream>>>(ref, pooled, xpad);
    attn_k<<<16, 256, 0, stream>>>(pooled, fc1w, fc2w, fc2b, bias, attn, aggb);
    aggw_k<<<dim3(32, 8), 256, 0, stream>>>(attn, weight, aggw);
    xpad_int_k<<<dim3(49, 4, 16), 256, 0, stream>>>(x, xpad);
    conv_k<<<224, 512, LDS_TOT, stream>>>(xpad, aggw, aggb, out);
}

// Round 9
// 118.406 us; speedup vs baseline: 1.0483x; 1.0483x over previous
//
#include <hip/hip_runtime.h>
#include <hip/hip_bf16.h>

// Problem constants
#define BB    16
#define CREF  256
#define CINC  256
#define COUTC 256
#define KKN   4
#define HH    56
#define WWW   56
#define HIDDEN 65
#define NPIX  3136          // 56*56
#define PPIX  3364          // 58*58 padded
#define TEMP  34.0f

typedef __bf16 bf16x8 __attribute__((ext_vector_type(8)));
typedef float  f32x4  __attribute__((ext_vector_type(4)));

// ---------------- ws layout (bytes) ----------------
#define WS_ATTN   0
#define WS_AGGB   4096
#define WS_POOL   24576
#define WS_AGGW   65536      // 16*2*8*36864 elems bf16 = 18,874,368 B  [b][ch][cb8][tap][cing][cout128][cin8]
#define WS_XPAD   19005440   // 16*3364*256*2 = 27,557,888 (+slack for staging overread)

#define ABUF  73728          // bytes per (b,ch,cb8) A slab: [tap9][cing4][cout128][16B]
#define XB_SZ 24576          // one X buffer: [cg4][row6][col64][16B]

// ---------- 1. adaptive avg pool (one wave per (b,c)) + xpad border zeroing ----------
__global__ void pool_k(const float* __restrict__ ref, float* __restrict__ pooled,
                       __bf16* __restrict__ xpad) {
    int wid = threadIdx.x >> 6, lane = threadIdx.x & 63;
    int gw = blockIdx.x * 4 + wid;            // 0..4095 = b*256+c
    const float4* r4 = reinterpret_cast<const float4*>(ref) + (size_t)gw * 784;
    float s = 0.f;
    for (int i = lane; i < 784; i += 64) {
        float4 v = r4[i];
        s += v.x + v.y + v.z + v.w;
    }
    for (int o = 32; o; o >>= 1) s += __shfl_xor(s, o);
    if (lane == 0) pooled[gw] = s * (1.0f / (float)NPIX);

    // border zeroing: 16 b * 228 border positions, 512B rows
    if (gw < 3648) {
        int b = gw / 228, i = gw % 228;
        int ph, pw;
        if (i < 58)       { ph = 0;        pw = i; }
        else if (i < 116) { ph = 57;       pw = i - 58; }
        else if (i < 172) { ph = i - 115;  pw = 0; }
        else              { ph = i - 171;  pw = 57; }
        uint2* dst = (uint2*)(xpad + ((size_t)b * PPIX + ph * 58 + pw) * 256);
        dst[lane] = (uint2){0u, 0u};
    }
}

// ---------- 2. attention + agg bias: one block per batch sample ----------
__global__ void attn_k(const float* __restrict__ pooled, const float* __restrict__ fc1w,
                       const float* __restrict__ fc2w, const float* __restrict__ fc2b,
                       const float* __restrict__ bias,
                       float* __restrict__ attn, float* __restrict__ aggb) {
    int b = blockIdx.x;
    int t = threadIdx.x;
    __shared__ float sh[HIDDEN + 7];
    __shared__ float sl[KKN];
    __shared__ float sa[KKN];
    const float* prow = pooled + b * CREF;
    {
        int j = t >> 2, sub = t & 3;
        const float4* w4 = (const float4*)(fc1w + j * CREF + sub * 64);
        const float4* p4 = (const float4*)(prow + sub * 64);
        float s = 0.f;
#pragma unroll
        for (int k = 0; k < 16; ++k) {
            float4 w = w4[k], p = p4[k];
            s += w.x * p.x + w.y * p.y + w.z * p.z + w.w * p.w;
        }
        s += __shfl_xor(s, 1); s += __shfl_xor(s, 2);
        if (sub == 0) sh[j] = fmaxf(s, 0.f);
    }
    if (t < 4) {   // j = 64
        const float4* w4 = (const float4*)(fc1w + 64 * CREF + t * 64);
        const float4* p4 = (const float4*)(prow + t * 64);
        float s = 0.f;
#pragma unroll
        for (int k = 0; k < 16; ++k) {
            float4 w = w4[k], p = p4[k];
            s += w.x * p.x + w.y * p.y + w.z * p.z + w.w * p.w;
        }
        s += __shfl_xor(s, 1); s += __shfl_xor(s, 2);
        if (t == 0) sh[64] = fmaxf(s, 0.f);
    }
    __syncthreads();
    if (t < KKN) {
        float s = fc2b[t];
        for (int j = 0; j < HIDDEN; ++j) s += sh[j] * fc2w[t * HIDDEN + j];
        sl[t] = s * (1.0f / TEMP);
    }
    __syncthreads();
    if (t == 0) {
        float m = fmaxf(fmaxf(sl[0], sl[1]), fmaxf(sl[2], sl[3]));
        float e0 = expf(sl[0] - m), e1 = expf(sl[1] - m);
        float e2 = expf(sl[2] - m), e3 = expf(sl[3] - m);
        float inv = 1.f / (e0 + e1 + e2 + e3);
        sa[0] = e0 * inv; sa[1] = e1 * inv; sa[2] = e2 * inv; sa[3] = e3 * inv;
        attn[b * 4 + 0] = sa[0]; attn[b * 4 + 1] = sa[1];
        attn[b * 4 + 2] = sa[2]; attn[b * 4 + 3] = sa[3];
    }
    __syncthreads();
    {
        float s = 0.f;
#pragma unroll
        for (int k = 0; k < KKN; ++k) s += sa[k] * bias[k * COUTC + t];
        aggb[b * COUTC + t] = s;
    }
}

// ---------- 3. blend weights -> bf16 [b][ch][cb8][tap][cing][cout128][cin8] ----------
// grid (32 cout-blocks, 8 cb8), block 256 = (cout 8) x (cr 32)
__global__ void aggw_k(const float* __restrict__ attn, const float* __restrict__ weight,
                       __bf16* __restrict__ aggw) {
    __shared__ float s_attn[64];
    int t = threadIdx.x;
    int co = t >> 5, cr = t & 31;
    int cout = blockIdx.x * 8 + co;       // 0..255
    int cb8 = blockIdx.y;                 // 0..7
    int cin = cb8 * 32 + cr;
    if (t < 64) s_attn[t] = attn[t];
    __syncthreads();
    float w[4][9];
#pragma unroll
    for (int k = 0; k < 4; ++k) {
        const float* wp = weight + ((size_t)(k * 256 + cout) * 256 + cin) * 9;
#pragma unroll
        for (int tp = 0; tp < 9; ++tp) w[k][tp] = wp[tp];
    }
    int ch = cout >> 7, coutl = cout & 127;
    int cing = cr >> 3, cinr = cr & 7;
    for (int b = 0; b < BB; ++b) {
        float a0 = s_attn[b * 4 + 0], a1 = s_attn[b * 4 + 1];
        float a2 = s_attn[b * 4 + 2], a3 = s_attn[b * 4 + 3];
#pragma unroll
        for (int tap = 0; tap < 9; ++tap) {
            float v = a0 * w[0][tap] + a1 * w[1][tap] + a2 * w[2][tap] + a3 * w[3][tap];
            size_t e = (size_t)((b * 2 + ch) * 8 + cb8) * 36864 +
                       (tap * 4 + cing) * 1024 + coutl * 8 + cinr;
            aggw[e] = (__bf16)v;
        }
    }
}

// ---------- 4. x -> padded NHWC bf16 (interior, tiled transpose) ----------
__global__ void xpad_int_k(const float* __restrict__ x, __bf16* __restrict__ xpad) {
    __shared__ float tile[64][65];
    int pt = blockIdx.x;      // 0..48 pixel tile (64 px)
    int cg = blockIdx.y;      // 0..3 cin group (64 cins)
    int b  = blockIdx.z;
    int q = threadIdx.x >> 6, l = threadIdx.x & 63;
    for (int k = 0; k < 16; ++k) {
        int cl = q * 16 + k;
        tile[cl][l] = x[((size_t)(b * 256 + cg * 64 + cl)) * NPIX + pt * 64 + l];
    }
    __syncthreads();
    for (int k = 0; k < 16; ++k) {
        int pl = q * 16 + k;
        int pixel = pt * 64 + pl;
        int h = pixel / 56, w = pixel - h * 56;
        xpad[(((size_t)b * PPIX + (h + 1) * 58 + (w + 1)) * 256) + cg * 64 + l] =
            (__bf16)tile[l][pl];
    }
}

// ---------- 5. conv: implicit GEMM. X via LDS (dbuf), A from global (L1/L2-resident) ----------
// block: 256 thr = 4 waves; wave = 128 couts x 56 px (1 row), Mr=8, Nr=4.
// block tile: 128 couts (ch half) x 4 rows. grid = 16b x 14rp x 2ch = 448, XCD-swizzled.
// LDS: X only, 2 x 24KB [cg4][row6][col64][16B] (+pad). ONE __syncthreads per cb8.
// A fragments prefetched one tap ahead into ping-pong registers (compiler-scheduled).
__global__ __launch_bounds__(256) void conv_k(const __bf16* __restrict__ xpad,
                                              const __bf16* __restrict__ aggw,
                                              const float* __restrict__ aggb,
                                              float* __restrict__ out) {
    __shared__ __attribute__((aligned(16))) char xs[2 * XB_SZ + 1024];  // +pad for col overread

    const int orig = blockIdx.x;
    const int logical = (orig & 7) * 56 + (orig >> 3);   // bijective, 448 = 8*56
    const int b  = logical / 28;
    const int r  = logical - b * 28;
    const int rp = r >> 1;            // 0..13 row-quad
    const int ch = r & 1;             // cout half
    const int tid = threadIdx.x;
    const int wid = tid >> 6, lane = tid & 63;
    const int l15 = lane & 15, l4 = lane >> 4;
    const int h0 = rp * 4;            // top padded row staged (rows h0..h0+5)

    const char* xb  = (const char*)xpad + (size_t)b * PPIX * 512;
    const char* awb = (const char*)aggw + (size_t)((b * 2 + ch) * 8) * ABUF;
    const int voff = l4 * 2048 + l15 * 16;   // lane offset within a tap's 8KB A slab

    f32x4 acc[8][4];
#pragma unroll
    for (int m = 0; m < 8; ++m)
#pragma unroll
        for (int n = 0; n < 4; ++n) acc[m][n] = (f32x4){0.f, 0.f, 0.f, 0.f};

    bf16x8 af[2][8];     // A frag ping-pong (indices static: tap loop unrolled)
    bf16x8 bfr[2][4];    // B frag ping-pong

    // stage X K-block c into buffer buf: 24 x 1KB, wave wid does cg=wid rows 0..5
    auto XSTAGE = [&](int buf, int c) {
#pragma unroll
        for (int j = 0; j < 6; ++j) {
            const char* src = xb + (size_t)((h0 + j) * 58 + lane) * 512 + c * 64 + wid * 16;
            __builtin_amdgcn_global_load_lds(
                (const __attribute__((address_space(1))) void*)src,
                (__attribute__((address_space(3))) void*)(xs + buf * XB_SZ + (wid * 6 + j) * 1024),
                16, 0, 0);
        }
    };

#define ALOAD(P, C, T) do { \
    const char* ap_ = awb + (size_t)(C) * ABUF + (T) * 8192 + voff; \
    _Pragma("unroll") \
    for (int m_ = 0; m_ < 8; ++m_) af[P][m_] = *(const bf16x8*)(ap_ + m_ * 256); \
} while (0)

#define BLOAD(P, T, LB) do { \
    const int kh_ = (T) / 3, kw_ = (T) - kh_ * 3; \
    _Pragma("unroll") \
    for (int nf_ = 0; nf_ < 4; ++nf_) \
        bfr[P][nf_] = *(const bf16x8*)((LB) + \
            (((l4 * 6 + wid + kh_) * 64) + nf_ * 16 + l15 + kw_) * 16); \
} while (0)

    // prologue: X(0) -> LDS, A(c=0,tap=0) -> af[0]
    XSTAGE(0, 0);
    ALOAD(0, 0, 0);
    __syncthreads();

    int cur = 0;
    for (int c = 0; c < 8; ++c) {
        if (c < 7) XSTAGE(cur ^ 1, c + 1);
        const char* lb = xs + cur * XB_SZ;
        BLOAD(0, 0, lb);
#pragma unroll
        for (int t = 0; t < 9; ++t) {
            const int p = t & 1, q = p ^ 1;
            if (t < 8) {
                ALOAD(q, c, t + 1);
                BLOAD(q, t + 1, lb);
            } else if (c < 7) {
                ALOAD(q, c + 1, 0);      // prefetch next cb8's tap 0
            }
            __builtin_amdgcn_s_setprio(1);
#pragma unroll
            for (int nf = 0; nf < 4; ++nf)
#pragma unroll
                for (int m = 0; m < 8; ++m)
                    acc[m][nf] = __builtin_amdgcn_mfma_f32_16x16x32_bf16(
                        af[p][m], bfr[p][nf], acc[m][nf], 0, 0, 0);
            __builtin_amdgcn_s_setprio(0);
        }
        if (c < 7) {
            // 9 taps flip parity: prefetched next-tap0 sits in af[1]; move to af[0]
#pragma unroll
            for (int m = 0; m < 8; ++m) af[0][m] = af[1][m];
        }
        __syncthreads();                  // drains vmcnt+lgkm: X(c+1) ready, buffers safe
        cur ^= 1;
    }
#undef ALOAD
#undef BLOAD

    const int row = rp * 4 + wid;             // output row
#pragma unroll
    for (int m = 0; m < 8; ++m) {
#pragma unroll
        for (int i = 0; i < 4; ++i) {
            int cout = ch * 128 + m * 16 + l4 * 4 + i;
            float bv = aggb[b * COUTC + cout];
            float* op = out + ((size_t)(b * COUTC + cout) * NPIX + row * 56);
#pragma unroll
            for (int nf = 0; nf < 3; ++nf)
                __builtin_nontemporal_store(acc[m][nf][i] + bv, op + nf * 16 + l15);
            if (l15 < 8)
                __builtin_nontemporal_store(acc[m][3][i] + bv, op + 48 + l15);
        }
    }
}

extern "C" void kernel_launch(void* const* d_in, const int* in_sizes, int n_in,
                              void* d_out, int out_size, void* d_ws, size_t ws_size,
                              hipStream_t stream) {
    (void)in_sizes; (void)n_in; (void)out_size; (void)ws_size;
    const float* ref    = (const float*)d_in[0];
    const float* x      = (const float*)d_in[1];
    const float* fc1w   = (const float*)d_in[2];
    const float* fc2w   = (const float*)d_in[3];
    const float* fc2b   = (const float*)d_in[4];
    const float* weight = (const float*)d_in[5];
    const float* bias   = (const float*)d_in[6];
    float* out = (float*)d_out;
    char* ws = (char*)d_ws;

    float*  attn   = (float*)(ws + WS_ATTN);
    float*  aggb   = (float*)(ws + WS_AGGB);
    float*  pooled = (float*)(ws + WS_POOL);
    __bf16* aggw   = (__bf16*)(ws + WS_AGGW);
    __bf16* xpad   = (__bf16*)(ws + WS_XPAD);

    pool_k<<<1024, 256, 0, stream>>>(ref, pooled, xpad);
    attn_k<<<16, 256, 0, stream>>>(pooled, fc1w, fc2w, fc2b, bias, attn, aggb);
    aggw_k<<<dim3(32, 8), 256, 0, stream>>>(attn, weight, aggw);
    xpad_int_k<<<dim3(49, 4, 16), 256, 0, stream>>>(x, xpad);
    conv_k<<<448, 256, 0, stream>>>(xpad, aggw, aggb, out);
}

// Round 10
// 102.968 us; speedup vs baseline: 1.2054x; 1.1499x over previous
//
#include <hip/hip_runtime.h>
#include <hip/hip_bf16.h>

// Problem constants
#define BB    16
#define CREF  256
#define CINC  256
#define COUTC 256
#define KKN   4
#define HH    56
#define WWW   56
#define HIDDEN 65
#define NPIX  3136          // 56*56
#define PPIX  3364          // 58*58 padded
#define TEMP  34.0f

typedef __bf16 bf16x8 __attribute__((ext_vector_type(8)));
typedef float  f32x4  __attribute__((ext_vector_type(4)));

// ---------------- ws layout (bytes) ----------------
#define WS_ATTN   0
#define WS_AGGB   4096
#define WS_POOL   24576
#define WS_AGGW   65536      // 16*2*8*36864 elems bf16 = 18,874,368 B  [b][ch][cb8][tap][cing][cout128][cin8]
#define WS_XPAD   19005440   // 16*3364*256*2 = 27,557,888 (+slack for staging overread)

#define ABUF  73728          // bytes per (b,ch,cb8) A slab: [tap9][cing4][cout128][16B]
#define XB_SZ 24576          // one X buffer: [cg4][row6][col64][16B]
#define ASLOT 8192           // one tap's A slab in LDS
#define LDS_TOT (2*XB_SZ + 4*ASLOT)   // 81,920 B -> 2 blocks/CU

// ---------- 1. adaptive avg pool (one wave per (b,c)) + xpad border zeroing ----------
__global__ void pool_k(const float* __restrict__ ref, float* __restrict__ pooled,
                       __bf16* __restrict__ xpad) {
    int wid = threadIdx.x >> 6, lane = threadIdx.x & 63;
    int gw = blockIdx.x * 4 + wid;            // 0..4095 = b*256+c
    const float4* r4 = reinterpret_cast<const float4*>(ref) + (size_t)gw * 784;
    float s = 0.f;
    for (int i = lane; i < 784; i += 64) {
        float4 v = r4[i];
        s += v.x + v.y + v.z + v.w;
    }
    for (int o = 32; o; o >>= 1) s += __shfl_xor(s, o);
    if (lane == 0) pooled[gw] = s * (1.0f / (float)NPIX);

    // border zeroing: 16 b * 228 border positions, 512B rows
    if (gw < 3648) {
        int b = gw / 228, i = gw % 228;
        int ph, pw;
        if (i < 58)       { ph = 0;        pw = i; }
        else if (i < 116) { ph = 57;       pw = i - 58; }
        else if (i < 172) { ph = i - 115;  pw = 0; }
        else              { ph = i - 171;  pw = 57; }
        uint2* dst = (uint2*)(xpad + ((size_t)b * PPIX + ph * 58 + pw) * 256);
        dst[lane] = (uint2){0u, 0u};
    }
}

// ---------- 2. attention + agg bias: one block per batch sample ----------
__global__ void attn_k(const float* __restrict__ pooled, const float* __restrict__ fc1w,
                       const float* __restrict__ fc2w, const float* __restrict__ fc2b,
                       const float* __restrict__ bias,
                       float* __restrict__ attn, float* __restrict__ aggb) {
    int b = blockIdx.x;
    int t = threadIdx.x;
    __shared__ float sh[HIDDEN + 7];
    __shared__ float sl[KKN];
    __shared__ float sa[KKN];
    const float* prow = pooled + b * CREF;
    {
        int j = t >> 2, sub = t & 3;
        const float4* w4 = (const float4*)(fc1w + j * CREF + sub * 64);
        const float4* p4 = (const float4*)(prow + sub * 64);
        float s = 0.f;
#pragma unroll
        for (int k = 0; k < 16; ++k) {
            float4 w = w4[k], p = p4[k];
            s += w.x * p.x + w.y * p.y + w.z * p.z + w.w * p.w;
        }
        s += __shfl_xor(s, 1); s += __shfl_xor(s, 2);
        if (sub == 0) sh[j] = fmaxf(s, 0.f);
    }
    if (t < 4) {   // j = 64
        const float4* w4 = (const float4*)(fc1w + 64 * CREF + t * 64);
        const float4* p4 = (const float4*)(prow + t * 64);
        float s = 0.f;
#pragma unroll
        for (int k = 0; k < 16; ++k) {
            float4 w = w4[k], p = p4[k];
            s += w.x * p.x + w.y * p.y + w.z * p.z + w.w * p.w;
        }
        s += __shfl_xor(s, 1); s += __shfl_xor(s, 2);
        if (t == 0) sh[64] = fmaxf(s, 0.f);
    }
    __syncthreads();
    if (t < KKN) {
        float s = fc2b[t];
        for (int j = 0; j < HIDDEN; ++j) s += sh[j] * fc2w[t * HIDDEN + j];
        sl[t] = s * (1.0f / TEMP);
    }
    __syncthreads();
    if (t == 0) {
        float m = fmaxf(fmaxf(sl[0], sl[1]), fmaxf(sl[2], sl[3]));
        float e0 = expf(sl[0] - m), e1 = expf(sl[1] - m);
        float e2 = expf(sl[2] - m), e3 = expf(sl[3] - m);
        float inv = 1.f / (e0 + e1 + e2 + e3);
        sa[0] = e0 * inv; sa[1] = e1 * inv; sa[2] = e2 * inv; sa[3] = e3 * inv;
        attn[b * 4 + 0] = sa[0]; attn[b * 4 + 1] = sa[1];
        attn[b * 4 + 2] = sa[2]; attn[b * 4 + 3] = sa[3];
    }
    __syncthreads();
    {
        float s = 0.f;
#pragma unroll
        for (int k = 0; k < KKN; ++k) s += sa[k] * bias[k * COUTC + t];
        aggb[b * COUTC + t] = s;
    }
}

// ---------- 3. blend weights -> bf16 [b][ch][cb8][tap][cing][cout128][cin8] ----------
// grid (32 cout-blocks, 8 cb8), block 256 = (cout 8) x (cr 32)
__global__ void aggw_k(const float* __restrict__ attn, const float* __restrict__ weight,
                       __bf16* __restrict__ aggw) {
    __shared__ float s_attn[64];
    int t = threadIdx.x;
    int co = t >> 5, cr = t & 31;
    int cout = blockIdx.x * 8 + co;       // 0..255
    int cb8 = blockIdx.y;                 // 0..7
    int cin = cb8 * 32 + cr;
    if (t < 64) s_attn[t] = attn[t];
    __syncthreads();
    float w[4][9];
#pragma unroll
    for (int k = 0; k < 4; ++k) {
        const float* wp = weight + ((size_t)(k * 256 + cout) * 256 + cin) * 9;
#pragma unroll
        for (int tp = 0; tp < 9; ++tp) w[k][tp] = wp[tp];
    }
    int ch = cout >> 7, coutl = cout & 127;
    int cing = cr >> 3, cinr = cr & 7;
    for (int b = 0; b < BB; ++b) {
        float a0 = s_attn[b * 4 + 0], a1 = s_attn[b * 4 + 1];
        float a2 = s_attn[b * 4 + 2], a3 = s_attn[b * 4 + 3];
#pragma unroll
        for (int tap = 0; tap < 9; ++tap) {
            float v = a0 * w[0][tap] + a1 * w[1][tap] + a2 * w[2][tap] + a3 * w[3][tap];
            size_t e = (size_t)((b * 2 + ch) * 8 + cb8) * 36864 +
                       (tap * 4 + cing) * 1024 + coutl * 8 + cinr;
            aggw[e] = (__bf16)v;
        }
    }
}

// ---------- 4. x -> padded NHWC bf16 (interior, tiled transpose) ----------
__global__ void xpad_int_k(const float* __restrict__ x, __bf16* __restrict__ xpad) {
    __shared__ float tile[64][65];
    int pt = blockIdx.x;      // 0..48 pixel tile (64 px)
    int cg = blockIdx.y;      // 0..3 cin group (64 cins)
    int b  = blockIdx.z;
    int q = threadIdx.x >> 6, l = threadIdx.x & 63;
    for (int k = 0; k < 16; ++k) {
        int cl = q * 16 + k;
        tile[cl][l] = x[((size_t)(b * 256 + cg * 64 + cl)) * NPIX + pt * 64 + l];
    }
    __syncthreads();
    for (int k = 0; k < 16; ++k) {
        int pl = q * 16 + k;
        int pixel = pt * 64 + pl;
        int h = pixel / 56, w = pixel - h * 56;
        xpad[(((size_t)b * PPIX + (h + 1) * 58 + (w + 1)) * 256) + cg * 64 + l] =
            (__bf16)tile[l][pl];
    }
}

// ---------- 5. conv: implicit GEMM. X dbuf + A 4-slot tap-ring, both in LDS ----------
// block: 256 thr = 4 waves; wave = 128 couts x 56 px (1 row), Mr=8, Nr=4.
// grid = 16b x 14rp x 2ch = 448, XCD-swizzled. LDS 80KB -> 2 blocks/CU.
// Per tap t of cb8 c: stage A(t+3) into ring slot (c+t+3)&3 (2 loads/wave);
// X(c+1) staged at t==5; prefetch frags(t+1) into ping-pong regs; 32 MFMA;
// counted-vmcnt barrier (steady state 2, around X 8, never 0 until the tail).
__global__ __launch_bounds__(256, 2) void conv_k(const __bf16* __restrict__ xpad,
                                                 const __bf16* __restrict__ aggw,
                                                 const float* __restrict__ aggb,
                                                 float* __restrict__ out) {
    extern __shared__ __attribute__((aligned(16))) char smem[];
    char* xs = smem;                  // 2 x 24KB X buffers
    char* as = smem + 2 * XB_SZ;      // 4 x 8KB A ring

    const int orig = blockIdx.x;
    const int logical = (orig & 7) * 56 + (orig >> 3);   // bijective, 448 = 8*56
    const int b  = logical / 28;
    const int r  = logical - b * 28;
    const int rp = r >> 1;            // 0..13 row-quad
    const int ch = r & 1;             // cout half
    const int tid = threadIdx.x;
    const int wid = tid >> 6, lane = tid & 63;
    const int l15 = lane & 15, l4 = lane >> 4;
    const int h0 = rp * 4;            // top padded row staged (rows h0..h0+5)

    const char* xb  = (const char*)xpad + (size_t)b * PPIX * 512;
    const char* awb = (const char*)aggw + (size_t)((b * 2 + ch) * 8) * ABUF;

    f32x4 acc[8][4];
#pragma unroll
    for (int m = 0; m < 8; ++m)
#pragma unroll
        for (int n = 0; n < 4; ++n) acc[m][n] = (f32x4){0.f, 0.f, 0.f, 0.f};

    bf16x8 af[2][8];     // A frag ping-pong (static indices, tap loop unrolled)
    bf16x8 bfr[2][4];    // B frag ping-pong

    // stage X K-block c into buffer buf: 24 x 1KB, wave wid does cg=wid rows 0..5
    auto XSTAGE = [&](int buf, int c) {
#pragma unroll
        for (int j = 0; j < 6; ++j) {
            const char* src = xb + (size_t)((h0 + j) * 58 + lane) * 512 + c * 64 + wid * 16;
            __builtin_amdgcn_global_load_lds(
                (const __attribute__((address_space(1))) void*)src,
                (__attribute__((address_space(3))) void*)(xs + buf * XB_SZ + (wid * 6 + j) * 1024),
                16, 0, 0);
        }
    };
    // stage one tap's 8KB A slab into ring slot: 8 x 1KB, 2 per wave
    auto ASTAGE = [&](int slot, int c, int tap) {
#pragma unroll
        for (int j = 0; j < 2; ++j) {
            int k = wid * 2 + j;
            const char* src = awb + (size_t)c * ABUF + tap * 8192 + k * 1024 + lane * 16;
            __builtin_amdgcn_global_load_lds(
                (const __attribute__((address_space(1))) void*)src,
                (__attribute__((address_space(3))) void*)(as + slot * ASLOT + k * 1024),
                16, 0, 0);
        }
    };

#define ALOADF(P, SLOT) do { \
    const char* ap_ = as + (SLOT) * ASLOT + l4 * 2048 + l15 * 16; \
    _Pragma("unroll") \
    for (int m_ = 0; m_ < 8; ++m_) af[P][m_] = *(const bf16x8*)(ap_ + m_ * 256); \
} while (0)

#define BLOADF(P, T, LB) do { \
    const int kh_ = (T) / 3, kw_ = (T) - kh_ * 3; \
    _Pragma("unroll") \
    for (int nf_ = 0; nf_ < 4; ++nf_) \
        bfr[P][nf_] = *(const bf16x8*)((LB) + \
            (((l4 * 6 + wid + kh_) * 64) + nf_ * 16 + l15 + kw_) * 16); \
} while (0)

#define MFMAS(P) do { \
    __builtin_amdgcn_s_setprio(1); \
    _Pragma("unroll") \
    for (int nf_ = 0; nf_ < 4; ++nf_) \
        _Pragma("unroll") \
        for (int m_ = 0; m_ < 8; ++m_) \
            acc[m_][nf_] = __builtin_amdgcn_mfma_f32_16x16x32_bf16( \
                af[P][m_], bfr[P][nf_], acc[m_][nf_], 0, 0, 0); \
    __builtin_amdgcn_s_setprio(0); \
} while (0)

#define SUBBAR(N) do { \
        asm volatile("s_waitcnt vmcnt(" #N ")" ::: "memory"); \
        __builtin_amdgcn_s_barrier(); \
        __builtin_amdgcn_sched_barrier(0); } while (0)

    // prologue: X(0); A taps 0,1,2 -> slots 0,1,2; full drain once; tap-0 frags
    XSTAGE(0, 0);
    ASTAGE(0, 0, 0);
    ASTAGE(1, 0, 1);
    ASTAGE(2, 0, 2);
    SUBBAR(0);
    ALOADF(0, 0);
    BLOADF(0, 0, xs);

    int cur = 0;
    for (int c = 0; c < 8; ++c) {
        const int cs = c & 3;
        const char* lb  = xs + cur * XB_SZ;
        const char* lbn = xs + (cur ^ 1) * XB_SZ;
#pragma unroll
        for (int t = 0; t < 9; ++t) {
            const int p = t & 1, q = p ^ 1;
            // stage A for tap t+3 (this or next cb8) into ring slot (c+t+3)&3
            if (t < 6) {
                ASTAGE((t + cs + 3) & 3, c, t + 3);
            } else if (c < 7) {
                ASTAGE((t + cs + 3) & 3, c + 1, t - 6);
            }
            if (t == 5 && c < 7) XSTAGE(cur ^ 1, c + 1);
            // prefetch frags for next tap
            if (t < 8) {
                ALOADF(q, (t + 1 + cs) & 3);
                BLOADF(q, t + 1, lb);
            } else if (c < 7) {
                ALOADF(q, (cs + 1) & 3);     // next cb8 tap 0 (staged at t==6)
                BLOADF(q, 0, lbn);           // from X(c+1)
            }
            MFMAS(p);
            // counted-vmcnt barrier (per-wave FIFO ledger; see round notes)
            if (t <= 4)      { SUBBAR(2); }
            else if (t == 5) { if (c < 7) SUBBAR(8); else SUBBAR(2); }
            else if (t == 6) { if (c < 7) SUBBAR(8); else SUBBAR(0); }
            else if (t == 7) { if (c < 7) SUBBAR(2); else SUBBAR(0); }
            else             { if (c < 7) SUBBAR(2); /* last tap of all: none */ }
        }
        if (c < 7) {
            // 9 taps flip parity: prefetched next-tap0 frags sit in [1]; move to [0]
#pragma unroll
            for (int m = 0; m < 8; ++m) af[0][m] = af[1][m];
#pragma unroll
            for (int n = 0; n < 4; ++n) bfr[0][n] = bfr[1][n];
        }
        cur ^= 1;
    }
#undef ALOADF
#undef BLOADF
#undef MFMAS
#undef SUBBAR

    const int row = rp * 4 + wid;             // output row
#pragma unroll
    for (int m = 0; m < 8; ++m) {
#pragma unroll
        for (int i = 0; i < 4; ++i) {
            int cout = ch * 128 + m * 16 + l4 * 4 + i;
            float bv = aggb[b * COUTC + cout];
            float* op = out + ((size_t)(b * COUTC + cout) * NPIX + row * 56);
#pragma unroll
            for (int nf = 0; nf < 3; ++nf)
                __builtin_nontemporal_store(acc[m][nf][i] + bv, op + nf * 16 + l15);
            if (l15 < 8)
                __builtin_nontemporal_store(acc[m][3][i] + bv, op + 48 + l15);
        }
    }
}

extern "C" void kernel_launch(void* const* d_in, const int* in_sizes, int n_in,
                              void* d_out, int out_size, void* d_ws, size_t ws_size,
                              hipStream_t stream) {
    (void)in_sizes; (void)n_in; (void)out_size; (void)ws_size;
    const float* ref    = (const float*)d_in[0];
    const float* x      = (const float*)d_in[1];
    const float* fc1w   = (const float*)d_in[2];
    const float* fc2w   = (const float*)d_in[3];
    const float* fc2b   = (const float*)d_in[4];
    const float* weight = (const float*)d_in[5];
    const float* bias   = (const float*)d_in[6];
    float* out = (float*)d_out;
    char* ws = (char*)d_ws;

    float*  attn   = (float*)(ws + WS_ATTN);
    float*  aggb   = (float*)(ws + WS_AGGB);
    float*  pooled = (float*)(ws + WS_POOL);
    __bf16* aggw   = (__bf16*)(ws + WS_AGGW);
    __bf16* xpad   = (__bf16*)(ws + WS_XPAD);

    // allow >64KB dynamic LDS for conv_k (deterministic, capture-safe host call)
    hipFuncSetAttribute((const void*)conv_k,
                        hipFuncAttributeMaxDynamicSharedMemorySize, LDS_TOT);

    pool_k<<<1024, 256, 0, stream>>>(ref, pooled, xpad);
    attn_k<<<16, 256, 0, stream>>>(pooled, fc1w, fc2w, fc2b, bias, attn, aggb);
    aggw_k<<<dim3(32, 8), 256, 0, stream>>>(attn, weight, aggw);
    xpad_int_k<<<dim3(49, 4, 16), 256, 0, stream>>>(x, xpad);
    conv_k<<<448, 256, LDS_TOT, stream>>>(xpad, aggw, aggb, out);
}

// Round 11
// 98.482 us; speedup vs baseline: 1.2604x; 1.0456x over previous
//
#include <hip/hip_runtime.h>
#include <hip/hip_bf16.h>

// Problem constants
#define BB    16
#define CREF  256
#define CINC  256
#define COUTC 256
#define KKN   4
#define HH    56
#define WWW   56
#define HIDDEN 65
#define NPIX  3136          // 56*56
#define PPIX  3364          // 58*58 padded
#define TEMP  34.0f

typedef __bf16 bf16x8 __attribute__((ext_vector_type(8)));
typedef float  f32x4  __attribute__((ext_vector_type(4)));

// ---------------- ws layout (bytes) ----------------
#define WS_ATTN   0
#define WS_AGGB   4096
#define WS_POOL   24576
#define WS_AGGW   65536      // 16*2*8*36864 elems bf16 = 18,874,368 B  [b][ch][cb8][tap][cing][cout128][cin8]
#define WS_XPAD   19005440   // 16*3364*256*2 = 27,557,888 (+slack for staging overread)

#define ABUF  73728          // bytes per (b,ch,cb8) A slab: [tap9][cing4][cout128][16B]
#define XB_SZ 24576          // one X buffer: [cg4][row6][col64][16B]
#define ASLOT 8192           // one tap's A slab in LDS
#define LDS_TOT (2*XB_SZ + 4*ASLOT)   // 81,920 B -> 2 blocks/CU

// ---------- 1. adaptive avg pool (one wave per (b,c)) + xpad border zeroing ----------
__global__ void pool_k(const float* __restrict__ ref, float* __restrict__ pooled,
                       __bf16* __restrict__ xpad) {
    int wid = threadIdx.x >> 6, lane = threadIdx.x & 63;
    int gw = blockIdx.x * 4 + wid;            // 0..4095 = b*256+c
    const float4* r4 = reinterpret_cast<const float4*>(ref) + (size_t)gw * 784;
    float s = 0.f;
    for (int i = lane; i < 784; i += 64) {
        float4 v = r4[i];
        s += v.x + v.y + v.z + v.w;
    }
    for (int o = 32; o; o >>= 1) s += __shfl_xor(s, o);
    if (lane == 0) pooled[gw] = s * (1.0f / (float)NPIX);

    // border zeroing: 16 b * 228 border positions, 512B rows
    if (gw < 3648) {
        int b = gw / 228, i = gw % 228;
        int ph, pw;
        if (i < 58)       { ph = 0;        pw = i; }
        else if (i < 116) { ph = 57;       pw = i - 58; }
        else if (i < 172) { ph = i - 115;  pw = 0; }
        else              { ph = i - 171;  pw = 57; }
        uint2* dst = (uint2*)(xpad + ((size_t)b * PPIX + ph * 58 + pw) * 256);
        dst[lane] = (uint2){0u, 0u};
    }
}

// ---------- 2. attention + agg bias: one block per batch sample ----------
__global__ void attn_k(const float* __restrict__ pooled, const float* __restrict__ fc1w,
                       const float* __restrict__ fc2w, const float* __restrict__ fc2b,
                       const float* __restrict__ bias,
                       float* __restrict__ attn, float* __restrict__ aggb) {
    int b = blockIdx.x;
    int t = threadIdx.x;
    __shared__ float sh[HIDDEN + 7];
    __shared__ float sl[KKN];
    __shared__ float sa[KKN];
    const float* prow = pooled + b * CREF;
    {
        int j = t >> 2, sub = t & 3;
        const float4* w4 = (const float4*)(fc1w + j * CREF + sub * 64);
        const float4* p4 = (const float4*)(prow + sub * 64);
        float s = 0.f;
#pragma unroll
        for (int k = 0; k < 16; ++k) {
            float4 w = w4[k], p = p4[k];
            s += w.x * p.x + w.y * p.y + w.z * p.z + w.w * p.w;
        }
        s += __shfl_xor(s, 1); s += __shfl_xor(s, 2);
        if (sub == 0) sh[j] = fmaxf(s, 0.f);
    }
    if (t < 4) {   // j = 64
        const float4* w4 = (const float4*)(fc1w + 64 * CREF + t * 64);
        const float4* p4 = (const float4*)(prow + t * 64);
        float s = 0.f;
#pragma unroll
        for (int k = 0; k < 16; ++k) {
            float4 w = w4[k], p = p4[k];
            s += w.x * p.x + w.y * p.y + w.z * p.z + w.w * p.w;
        }
        s += __shfl_xor(s, 1); s += __shfl_xor(s, 2);
        if (t == 0) sh[64] = fmaxf(s, 0.f);
    }
    __syncthreads();
    if (t < KKN) {
        float s = fc2b[t];
        for (int j = 0; j < HIDDEN; ++j) s += sh[j] * fc2w[t * HIDDEN + j];
        sl[t] = s * (1.0f / TEMP);
    }
    __syncthreads();
    if (t == 0) {
        float m = fmaxf(fmaxf(sl[0], sl[1]), fmaxf(sl[2], sl[3]));
        float e0 = expf(sl[0] - m), e1 = expf(sl[1] - m);
        float e2 = expf(sl[2] - m), e3 = expf(sl[3] - m);
        float inv = 1.f / (e0 + e1 + e2 + e3);
        sa[0] = e0 * inv; sa[1] = e1 * inv; sa[2] = e2 * inv; sa[3] = e3 * inv;
        attn[b * 4 + 0] = sa[0]; attn[b * 4 + 1] = sa[1];
        attn[b * 4 + 2] = sa[2]; attn[b * 4 + 3] = sa[3];
    }
    __syncthreads();
    {
        float s = 0.f;
#pragma unroll
        for (int k = 0; k < KKN; ++k) s += sa[k] * bias[k * COUTC + t];
        aggb[b * COUTC + t] = s;
    }
}

// ---------- 3. blend weights -> bf16 [b][ch][cb8][tap][cing][cout128][cin8] ----------
// grid (32 cout-blocks, 8 cb8), block 256 = (cout 8) x (cr 32)
__global__ void aggw_k(const float* __restrict__ attn, const float* __restrict__ weight,
                       __bf16* __restrict__ aggw) {
    __shared__ float s_attn[64];
    int t = threadIdx.x;
    int co = t >> 5, cr = t & 31;
    int cout = blockIdx.x * 8 + co;       // 0..255
    int cb8 = blockIdx.y;                 // 0..7
    int cin = cb8 * 32 + cr;
    if (t < 64) s_attn[t] = attn[t];
    __syncthreads();
    float w[4][9];
#pragma unroll
    for (int k = 0; k < 4; ++k) {
        const float* wp = weight + ((size_t)(k * 256 + cout) * 256 + cin) * 9;
#pragma unroll
        for (int tp = 0; tp < 9; ++tp) w[k][tp] = wp[tp];
    }
    int ch = cout >> 7, coutl = cout & 127;
    int cing = cr >> 3, cinr = cr & 7;
    for (int b = 0; b < BB; ++b) {
        float a0 = s_attn[b * 4 + 0], a1 = s_attn[b * 4 + 1];
        float a2 = s_attn[b * 4 + 2], a3 = s_attn[b * 4 + 3];
#pragma unroll
        for (int tap = 0; tap < 9; ++tap) {
            float v = a0 * w[0][tap] + a1 * w[1][tap] + a2 * w[2][tap] + a3 * w[3][tap];
            size_t e = (size_t)((b * 2 + ch) * 8 + cb8) * 36864 +
                       (tap * 4 + cing) * 1024 + coutl * 8 + cinr;
            aggw[e] = (__bf16)v;
        }
    }
}

// ---------- 4. x -> padded NHWC bf16 (interior, tiled transpose) ----------
__global__ void xpad_int_k(const float* __restrict__ x, __bf16* __restrict__ xpad) {
    __shared__ float tile[64][65];
    int pt = blockIdx.x;      // 0..48 pixel tile (64 px)
    int cg = blockIdx.y;      // 0..3 cin group (64 cins)
    int b  = blockIdx.z;
    int q = threadIdx.x >> 6, l = threadIdx.x & 63;
    for (int k = 0; k < 16; ++k) {
        int cl = q * 16 + k;
        tile[cl][l] = x[((size_t)(b * 256 + cg * 64 + cl)) * NPIX + pt * 64 + l];
    }
    __syncthreads();
    for (int k = 0; k < 16; ++k) {
        int pl = q * 16 + k;
        int pixel = pt * 64 + pl;
        int h = pixel / 56, w = pixel - h * 56;
        xpad[(((size_t)b * PPIX + (h + 1) * 58 + (w + 1)) * 256) + cg * 64 + l] =
            (__bf16)tile[l][pl];
    }
}

// ---------- 5. conv: implicit GEMM. X dbuf + A 4-slot tap-ring, template phase discipline ----------
// block: 256 thr = 4 waves; wave = 128 couts x 56 px (1 row), Mr=8, Nr=4.
// grid = 16b x 14rp x 2ch = 448, XCD-swizzled. LDS 80KB -> 2 blocks/CU (anti-phase overlap).
// Per tap (phase): [stage issues] -> [12 direct ds_reads] -> s_barrier(counted vmcnt)
//                  -> lgkmcnt(0) -> setprio(1) 32 MFMA setprio(0).
// Ledger: A(g) staged at global tap g-3, read at tap g start (2 barriers of slack);
// slot g%4 overwritten at tap g+3 (>=1 barrier after last read). vmcnt: 4 steady,
// 10 while X in flight (t=5..7), taper 4/2/0 in the last cb8.
__global__ __launch_bounds__(256, 2) void conv_k(const __bf16* __restrict__ xpad,
                                                 const __bf16* __restrict__ aggw,
                                                 const float* __restrict__ aggb,
                                                 float* __restrict__ out) {
    extern __shared__ __attribute__((aligned(16))) char smem[];
    char* xs = smem;                  // 2 x 24KB X buffers
    char* as = smem + 2 * XB_SZ;      // 4 x 8KB A ring

    const int orig = blockIdx.x;
    const int logical = (orig & 7) * 56 + (orig >> 3);   // bijective, 448 = 8*56
    const int b  = logical / 28;
    const int r  = logical - b * 28;
    const int rp = r >> 1;            // 0..13 row-quad
    const int ch = r & 1;             // cout half
    const int tid = threadIdx.x;
    const int wid = tid >> 6, lane = tid & 63;
    const int l15 = lane & 15, l4 = lane >> 4;
    const int h0 = rp * 4;            // top padded row staged (rows h0..h0+5)

    const char* xb  = (const char*)xpad + (size_t)b * PPIX * 512;
    const char* awb = (const char*)aggw + (size_t)((b * 2 + ch) * 8) * ABUF;

    f32x4 acc[8][4];
#pragma unroll
    for (int m = 0; m < 8; ++m)
#pragma unroll
        for (int n = 0; n < 4; ++n) acc[m][n] = (f32x4){0.f, 0.f, 0.f, 0.f};

    bf16x8 af[8];     // A fragments (direct use, single set)
    bf16x8 bfr[4];    // B fragments

    // stage X K-block c into buffer buf: 24 x 1KB, wave wid does cg=wid rows 0..5
    auto XSTAGE = [&](int buf, int c) {
#pragma unroll
        for (int j = 0; j < 6; ++j) {
            const char* src = xb + (size_t)((h0 + j) * 58 + lane) * 512 + c * 64 + wid * 16;
            __builtin_amdgcn_global_load_lds(
                (const __attribute__((address_space(1))) void*)src,
                (__attribute__((address_space(3))) void*)(xs + buf * XB_SZ + (wid * 6 + j) * 1024),
                16, 0, 0);
        }
    };
    // stage one tap's 8KB A slab into ring slot: 8 x 1KB, 2 per wave
    auto ASTAGE = [&](int slot, int c, int tap) {
#pragma unroll
        for (int j = 0; j < 2; ++j) {
            int k = wid * 2 + j;
            const char* src = awb + (size_t)c * ABUF + tap * 8192 + k * 1024 + lane * 16;
            __builtin_amdgcn_global_load_lds(
                (const __attribute__((address_space(1))) void*)src,
                (__attribute__((address_space(3))) void*)(as + slot * ASLOT + k * 1024),
                16, 0, 0);
        }
    };

#define ALOADF(SLOT) do { \
    const char* ap_ = as + (SLOT) * ASLOT + l4 * 2048 + l15 * 16; \
    _Pragma("unroll") \
    for (int m_ = 0; m_ < 8; ++m_) af[m_] = *(const bf16x8*)(ap_ + m_ * 256); \
} while (0)

#define BLOADF(T, LB) do { \
    const int kh_ = (T) / 3, kw_ = (T) - kh_ * 3; \
    _Pragma("unroll") \
    for (int nf_ = 0; nf_ < 4; ++nf_) \
        bfr[nf_] = *(const bf16x8*)((LB) + \
            (((l4 * 6 + wid + kh_) * 64) + nf_ * 16 + l15 + kw_) * 16); \
} while (0)

#define MFMAS() do { \
    __builtin_amdgcn_s_setprio(1); \
    _Pragma("unroll") \
    for (int nf_ = 0; nf_ < 4; ++nf_) \
        _Pragma("unroll") \
        for (int m_ = 0; m_ < 8; ++m_) \
            acc[m_][nf_] = __builtin_amdgcn_mfma_f32_16x16x32_bf16( \
                af[m_], bfr[nf_], acc[m_][nf_], 0, 0, 0); \
    __builtin_amdgcn_s_setprio(0); \
} while (0)

#define SUBBAR(N) do { \
        asm volatile("s_waitcnt vmcnt(" #N ")" ::: "memory"); \
        __builtin_amdgcn_s_barrier(); \
        __builtin_amdgcn_sched_barrier(0); } while (0)

#define LGKM0 do { \
        asm volatile("s_waitcnt lgkmcnt(0)" ::: "memory"); \
        __builtin_amdgcn_sched_barrier(0); } while (0)

    // prologue: X(0); A taps 0,1,2 -> slots 0,1,2; full drain once
    XSTAGE(0, 0);
    ASTAGE(0, 0, 0);
    ASTAGE(1, 0, 1);
    ASTAGE(2, 0, 2);
    SUBBAR(0);

    int cur = 0;
    for (int c = 0; c < 8; ++c) {
        const int cs = c & 3;
        const char* lb = xs + cur * XB_SZ;
#pragma unroll
        for (int t = 0; t < 9; ++t) {
            // ---- stage issues (A for global tap g+3; X at t==5) ----
            if (c < 7) {
                if (t < 6) ASTAGE((t + cs + 3) & 3, c, t + 3);
                else       ASTAGE((t + cs + 3) & 3, c + 1, t - 6);
                if (t == 5) XSTAGE(cur ^ 1, c + 1);
            } else {
                if (t < 6) ASTAGE((t + cs + 3) & 3, 7, t + 3);
            }
            // ---- direct fragment reads for THIS tap ----
            ALOADF((t + cs) & 3);
            BLOADF(t, lb);
            // ---- barrier with counted vmcnt (per-wave FIFO ledger) ----
            if (c < 7) {
                if (t <= 4 || t == 8) SUBBAR(4); else SUBBAR(10);
            } else {
                if (t <= 5)      { SUBBAR(4); }
                else if (t == 6) { SUBBAR(2); }
                else if (t == 7) { SUBBAR(0); }
                // t == 8: no barrier needed (epilogue follows)
            }
            LGKM0;
            MFMAS();
        }
        cur ^= 1;
    }
#undef ALOADF
#undef BLOADF
#undef MFMAS
#undef SUBBAR
#undef LGKM0

    const int row = rp * 4 + wid;             // output row
#pragma unroll
    for (int m = 0; m < 8; ++m) {
#pragma unroll
        for (int i = 0; i < 4; ++i) {
            int cout = ch * 128 + m * 16 + l4 * 4 + i;
            float bv = aggb[b * COUTC + cout];
            float* op = out + ((size_t)(b * COUTC + cout) * NPIX + row * 56);
#pragma unroll
            for (int nf = 0; nf < 3; ++nf)
                __builtin_nontemporal_store(acc[m][nf][i] + bv, op + nf * 16 + l15);
            if (l15 < 8)
                __builtin_nontemporal_store(acc[m][3][i] + bv, op + 48 + l15);
        }
    }
}

extern "C" void kernel_launch(void* const* d_in, const int* in_sizes, int n_in,
                              void* d_out, int out_size, void* d_ws, size_t ws_size,
                              hipStream_t stream) {
    (void)in_sizes; (void)n_in; (void)out_size; (void)ws_size;
    const float* ref    = (const float*)d_in[0];
    const float* x      = (const float*)d_in[1];
    const float* fc1w   = (const float*)d_in[2];
    const float* fc2w   = (const float*)d_in[3];
    const float* fc2b   = (const float*)d_in[4];
    const float* weight = (const float*)d_in[5];
    const float* bias   = (const float*)d_in[6];
    float* out = (float*)d_out;
    char* ws = (char*)d_ws;

    float*  attn   = (float*)(ws + WS_ATTN);
    float*  aggb   = (float*)(ws + WS_AGGB);
    float*  pooled = (float*)(ws + WS_POOL);
    __bf16* aggw   = (__bf16*)(ws + WS_AGGW);
    __bf16* xpad   = (__bf16*)(ws + WS_XPAD);

    // allow >64KB dynamic LDS for conv_k (deterministic, capture-safe host call)
    hipFuncSetAttribute((const void*)conv_k,
                        hipFuncAttributeMaxDynamicSharedMemorySize, LDS_TOT);

    pool_k<<<1024, 256, 0, stream>>>(ref, pooled, xpad);
    attn_k<<<16, 256, 0, stream>>>(pooled, fc1w, fc2w, fc2b, bias, attn, aggb);
    aggw_k<<<dim3(32, 8), 256, 0, stream>>>(attn, weight, aggw);
    xpad_int_k<<<dim3(49, 4, 16), 256, 0, stream>>>(x, xpad);
    conv_k<<<448, 256, LDS_TOT, stream>>>(xpad, aggw, aggb, out);
}